// Round 3
// baseline (1828.555 us; speedup 1.0000x reference)
//
#include <hip/hip_runtime.h>
#include <hip/hip_bf16.h>

typedef __hip_bfloat16 bf16;

#define NSLICE 32   // B*S
#define HW     1024 // H*W
#define CDIM   256  // C1 == C2 == C
#define QT     64   // q-tile tokens per block
#define KT     64   // k-tile tokens per iteration

// ---------------------------------------------------------------------------
// Kernel 1: QKV projection.
//   img/dep : [slice][C][HW] f32 (channel-major, as given)
//   q,k,v   : [slice][HW][C] bf16 (token-major) into workspace
// ---------------------------------------------------------------------------
__global__ __launch_bounds__(256)
void qkv_proj_kernel(const float* __restrict__ img, const float* __restrict__ dep,
                     const float* __restrict__ Wq, const float* __restrict__ bq,
                     const float* __restrict__ Wk, const float* __restrict__ bk,
                     const float* __restrict__ Wv, const float* __restrict__ bv,
                     bf16* __restrict__ qo, bf16* __restrict__ ko, bf16* __restrict__ vo)
{
    const int t0 = blockIdx.x * 64;   // token tile base
    const int c0 = blockIdx.y * 64;   // out-channel tile base
    const int s  = blockIdx.z;        // slice
    const int tid = threadIdx.x;
    const int tx = tid & 15, ty = tid >> 4;

    __shared__ float As_i[16][64];
    __shared__ float As_d[16][64];
    __shared__ float Wqs[16][64];
    __shared__ float Wks[16][64];
    __shared__ float Wvs[16][64];

    float aq[4][4] = {{0}}, ak[4][4] = {{0}}, av[4][4] = {{0}};

    const float* imgS = img + (size_t)s * CDIM * HW;
    const float* depS = dep + (size_t)s * CDIM * HW;

    for (int k0 = 0; k0 < CDIM; k0 += 16) {
        const int col   = tid & 63;
        const int rbase = tid >> 6;
        #pragma unroll
        for (int r = 0; r < 4; ++r) {
            const int row = r * 4 + rbase;
            As_i[row][col] = imgS[(size_t)(k0 + row) * HW + t0 + col];
            As_d[row][col] = depS[(size_t)(k0 + row) * HW + t0 + col];
            Wqs[row][col]  = Wq[(k0 + row) * CDIM + c0 + col];
            Wks[row][col]  = Wk[(k0 + row) * CDIM + c0 + col];
            Wvs[row][col]  = Wv[(k0 + row) * CDIM + c0 + col];
        }
        __syncthreads();
        #pragma unroll
        for (int kk = 0; kk < 16; ++kk) {
            float ai[4], ad[4], wq[4], wk[4], wv[4];
            #pragma unroll
            for (int i = 0; i < 4; ++i) {
                ai[i] = As_i[kk][ty * 4 + i];
                ad[i] = As_d[kk][ty * 4 + i];
                wq[i] = Wqs[kk][tx * 4 + i];
                wk[i] = Wks[kk][tx * 4 + i];
                wv[i] = Wvs[kk][tx * 4 + i];
            }
            #pragma unroll
            for (int i = 0; i < 4; ++i)
                #pragma unroll
                for (int j = 0; j < 4; ++j) {
                    aq[i][j] += ai[i] * wq[j];
                    ak[i][j] += ad[i] * wk[j];
                    av[i][j] += ad[i] * wv[j];
                }
        }
        __syncthreads();
    }

    float bqv[4], bkv[4], bvv[4];
    #pragma unroll
    for (int j = 0; j < 4; ++j) {
        bqv[j] = bq[c0 + tx * 4 + j];
        bkv[j] = bk[c0 + tx * 4 + j];
        bvv[j] = bv[c0 + tx * 4 + j];
    }
    #pragma unroll
    for (int i = 0; i < 4; ++i) {
        const size_t row = (size_t)s * HW * CDIM + (size_t)(t0 + ty * 4 + i) * CDIM + c0 + tx * 4;
        bf16 tq[4], tk[4], tv[4];
        #pragma unroll
        for (int j = 0; j < 4; ++j) {
            tq[j] = __float2bfloat16(aq[i][j] + bqv[j]);
            tk[j] = __float2bfloat16(ak[i][j] + bkv[j]);
            tv[j] = __float2bfloat16(av[i][j] + bvv[j]);
        }
        *reinterpret_cast<uint2*>(&qo[row]) = *reinterpret_cast<uint2*>(tq);
        *reinterpret_cast<uint2*>(&ko[row]) = *reinterpret_cast<uint2*>(tk);
        *reinterpret_cast<uint2*>(&vo[row]) = *reinterpret_cast<uint2*>(tv);
    }
}

// ---------------------------------------------------------------------------
// Kernel 2: fused flash attention + residual + channel-major f32 output.
// One block = (slice, 64-token q-tile). Online softmax, no global score buf.
// ---------------------------------------------------------------------------
__global__ __launch_bounds__(256)
void flash_kernel(const bf16* __restrict__ q, const bf16* __restrict__ k,
                  const bf16* __restrict__ v, const float* __restrict__ img,
                  float* __restrict__ out)
{
    const int s  = blockIdx.x;
    const int t0 = blockIdx.y * QT;
    const int tid = threadIdx.x;
    const int tx = tid & 15, ty = tid >> 4;

    __shared__ unsigned short Qs[CDIM][QT];   // Q tile, [c][tok], bf16 bits (32 KB)
    __shared__ float Ks[16][68];              // K chunk [c_local][ktok]
    __shared__ float Ss[QT][68];              // scores / P tile
    __shared__ unsigned short Vs[16][CDIM];   // V chunk [j_local][c]
    __shared__ float mrow[QT], lrow[QT], rrow[QT];

    const bf16* qS = q + ((size_t)s * HW + t0) * CDIM;
    const bf16* kS = k + (size_t)s * HW * CDIM;
    const bf16* vS = v + (size_t)s * HW * CDIM;

    // stage Q tile: ws [tok][c] bf16 -> LDS [c][tok]
    {
        const int tok = tid >> 2;
        const int cb  = (tid & 3) * 8;
        for (int p = 0; p < 8; ++p) {
            const int c = cb + p * 32;
            uint4 raw = *reinterpret_cast<const uint4*>(qS + (size_t)tok * CDIM + c);
            const unsigned short* e = (const unsigned short*)&raw;
            #pragma unroll
            for (int u = 0; u < 8; ++u) Qs[c + u][tok] = e[u];
        }
    }
    if (tid < QT) { mrow[tid] = -1e30f; lrow[tid] = 0.f; }
    __syncthreads();

    float O[4][16];
    #pragma unroll
    for (int i = 0; i < 4; ++i)
        #pragma unroll
        for (int jc = 0; jc < 16; ++jc) O[i][jc] = 0.f;

    const int r  = tid >> 2;   // softmax row owned by this thread's quad
    const int q4 = tid & 3;

    for (int kt = 0; kt < HW / KT; ++kt) {
        // ---- phase A: S = scale * Q K^T (64x64) ----
        float sa[4][4] = {{0}};
        for (int c0 = 0; c0 < CDIM; c0 += 16) {
            __syncthreads();
            {
                const int cl = tid & 15, rl = tid >> 4;
                #pragma unroll
                for (int rr = 0; rr < 4; ++rr) {
                    const int row = rr * 16 + rl;
                    Ks[cl][row] = __bfloat162float(
                        kS[(size_t)(kt * KT + row) * CDIM + c0 + cl]);
                }
            }
            __syncthreads();
            #pragma unroll
            for (int kk = 0; kk < 16; ++kk) {
                float qv[4], kv[4];
                #pragma unroll
                for (int i = 0; i < 4; ++i) {
                    unsigned short b = Qs[c0 + kk][ty * 4 + i];
                    qv[i] = __bfloat162float(*reinterpret_cast<bf16*>(&b));
                    kv[i] = Ks[kk][tx * 4 + i];
                }
                #pragma unroll
                for (int i = 0; i < 4; ++i)
                    #pragma unroll
                    for (int j = 0; j < 4; ++j) sa[i][j] += qv[i] * kv[j];
            }
        }
        __syncthreads();
        #pragma unroll
        for (int i = 0; i < 4; ++i)
            #pragma unroll
            for (int j = 0; j < 4; ++j)
                Ss[ty * 4 + i][tx * 4 + j] = sa[i][j] * 0.0625f;
        __syncthreads();

        // ---- phase B: online softmax update (4 threads per row) ----
        {
            float pm = -1e30f;
            #pragma unroll
            for (int j = 0; j < 16; ++j) pm = fmaxf(pm, Ss[r][q4 * 16 + j]);
            pm = fmaxf(pm, __shfl_xor(pm, 1));
            pm = fmaxf(pm, __shfl_xor(pm, 2));
            const float mold = mrow[r];
            const float mnew = fmaxf(mold, pm);
            float ps = 0.f;
            #pragma unroll
            for (int j = 0; j < 16; ++j) {
                const float e = __expf(Ss[r][q4 * 16 + j] - mnew);
                Ss[r][q4 * 16 + j] = e;
                ps += e;
            }
            ps += __shfl_xor(ps, 1);
            ps += __shfl_xor(ps, 2);
            if (q4 == 0) {
                rrow[r] = __expf(mold - mnew);
                lrow[r] = lrow[r] * rrow[r] + ps;
                mrow[r] = mnew;
            }
        }
        __syncthreads();

        // ---- phase C: O = O*resc + P @ V ----
        float rs[4];
        #pragma unroll
        for (int i = 0; i < 4; ++i) rs[i] = rrow[ty * 4 + i];
        #pragma unroll
        for (int i = 0; i < 4; ++i)
            #pragma unroll
            for (int jc = 0; jc < 16; ++jc) O[i][jc] *= rs[i];

        for (int j0 = 0; j0 < KT; j0 += 16) {
            __syncthreads();
            {
                const int jj = tid >> 4;
                const int cv = (tid & 15) * 16;
                const bf16* src = vS + (size_t)(kt * KT + j0 + jj) * CDIM + cv;
                *reinterpret_cast<uint4*>(&Vs[jj][cv])     = reinterpret_cast<const uint4*>(src)[0];
                *reinterpret_cast<uint4*>(&Vs[jj][cv + 8]) = reinterpret_cast<const uint4*>(src)[1];
            }
            __syncthreads();
            #pragma unroll
            for (int jj = 0; jj < 16; ++jj) {
                float pv[4];
                #pragma unroll
                for (int i = 0; i < 4; ++i) pv[i] = Ss[ty * 4 + i][j0 + jj];
                float vv[16];
                #pragma unroll
                for (int jc = 0; jc < 16; ++jc) {
                    unsigned short b = Vs[jj][tx + 16 * jc];
                    vv[jc] = __bfloat162float(*reinterpret_cast<bf16*>(&b));
                }
                #pragma unroll
                for (int i = 0; i < 4; ++i)
                    #pragma unroll
                    for (int jc = 0; jc < 16; ++jc) O[i][jc] += pv[i] * vv[jc];
            }
        }
        __syncthreads();
    }

    // ---- epilogue: divide by l, add residual, store channel-major f32 ----
    float inv[4];
    #pragma unroll
    for (int i = 0; i < 4; ++i) inv[i] = 1.0f / lrow[ty * 4 + i];
    const float* imgS = img + (size_t)s * CDIM * HW;
    float*       outS = out + (size_t)s * CDIM * HW;
    #pragma unroll
    for (int jc = 0; jc < 16; ++jc) {
        const int c = tx + 16 * jc;
        const size_t base = (size_t)c * HW + t0 + ty * 4;
        const float4 r4 = *reinterpret_cast<const float4*>(imgS + base);
        float4 o4;
        o4.x = O[0][jc] * inv[0] + r4.x;
        o4.y = O[1][jc] * inv[1] + r4.y;
        o4.z = O[2][jc] * inv[2] + r4.z;
        o4.w = O[3][jc] * inv[3] + r4.w;
        *reinterpret_cast<float4*>(outS + base) = o4;
    }
}

// ---------------------------------------------------------------------------
extern "C" void kernel_launch(void* const* d_in, const int* in_sizes, int n_in,
                              void* d_out, int out_size, void* d_ws, size_t ws_size,
                              hipStream_t stream)
{
    const float* img = (const float*)d_in[0];
    const float* dep = (const float*)d_in[1];
    const float* Wq  = (const float*)d_in[2];
    const float* bq  = (const float*)d_in[3];
    const float* Wk  = (const float*)d_in[4];
    const float* bk  = (const float*)d_in[5];
    const float* Wv  = (const float*)d_in[6];
    const float* bv  = (const float*)d_in[7];
    float* out = (float*)d_out;

    const size_t npt  = (size_t)NSLICE * HW * CDIM;       // elements per tensor
    const size_t need = 3 * npt * sizeof(bf16);           // 48 MiB
    if (ws_size < need) {
        hipMemsetAsync(d_out, 0, (size_t)out_size * sizeof(float), stream);
        return;
    }

    bf16* q = (bf16*)d_ws;
    bf16* k = q + npt;
    bf16* v = k + npt;

    qkv_proj_kernel<<<dim3(16, 4, NSLICE), 256, 0, stream>>>(
        img, dep, Wq, bq, Wk, bk, Wv, bv, q, k, v);

    flash_kernel<<<dim3(NSLICE, 16), 256, 0, stream>>>(q, k, v, img, out);
}

// Round 4
// 278.214 us; speedup vs baseline: 6.5725x; 6.5725x over previous
//
#include <hip/hip_runtime.h>
#include <hip/hip_bf16.h>

typedef __hip_bfloat16 bf16;
typedef __attribute__((ext_vector_type(8))) short short8v;
typedef __attribute__((ext_vector_type(4))) float f32x4;

#define NSLICE 32   // B*S
#define HW     1024 // H*W
#define CDIM   256  // C1 == C2 == C
#define KVT    32   // kv tokens per inner tile

// ---------------------------------------------------------------------------
// Kernel 1: QKV projection (VALU GEMM, unchanged structure).
//   img/dep : [slice][C][HW] f32 (channel-major)
//   q,k     : [slice][HW][C] bf16 token-major; q PRESCALED by 1/16
//   vt      : [slice][C][HW] bf16 channel-major (transposed for PV B-frags)
// ---------------------------------------------------------------------------
__global__ __launch_bounds__(256)
void qkv_proj_kernel(const float* __restrict__ img, const float* __restrict__ dep,
                     const float* __restrict__ Wq, const float* __restrict__ bq,
                     const float* __restrict__ Wk, const float* __restrict__ bk,
                     const float* __restrict__ Wv, const float* __restrict__ bv,
                     bf16* __restrict__ qo, bf16* __restrict__ ko, bf16* __restrict__ vt)
{
    const int t0 = blockIdx.x * 64;
    const int c0 = blockIdx.y * 64;
    const int s  = blockIdx.z;
    const int tid = threadIdx.x;
    const int tx = tid & 15, ty = tid >> 4;

    __shared__ float As_i[16][64];
    __shared__ float As_d[16][64];
    __shared__ float Wqs[16][64];
    __shared__ float Wks[16][64];
    __shared__ float Wvs[16][64];

    float aq[4][4] = {{0}}, ak[4][4] = {{0}}, av[4][4] = {{0}};

    const float* imgS = img + (size_t)s * CDIM * HW;
    const float* depS = dep + (size_t)s * CDIM * HW;

    for (int k0 = 0; k0 < CDIM; k0 += 16) {
        const int col   = tid & 63;
        const int rbase = tid >> 6;
        #pragma unroll
        for (int r = 0; r < 4; ++r) {
            const int row = r * 4 + rbase;
            As_i[row][col] = imgS[(size_t)(k0 + row) * HW + t0 + col];
            As_d[row][col] = depS[(size_t)(k0 + row) * HW + t0 + col];
            Wqs[row][col]  = Wq[(k0 + row) * CDIM + c0 + col];
            Wks[row][col]  = Wk[(k0 + row) * CDIM + c0 + col];
            Wvs[row][col]  = Wv[(k0 + row) * CDIM + c0 + col];
        }
        __syncthreads();
        #pragma unroll
        for (int kk = 0; kk < 16; ++kk) {
            float ai[4], ad[4], wq[4], wk[4], wv[4];
            #pragma unroll
            for (int i = 0; i < 4; ++i) {
                ai[i] = As_i[kk][ty * 4 + i];
                ad[i] = As_d[kk][ty * 4 + i];
                wq[i] = Wqs[kk][tx * 4 + i];
                wk[i] = Wks[kk][tx * 4 + i];
                wv[i] = Wvs[kk][tx * 4 + i];
            }
            #pragma unroll
            for (int i = 0; i < 4; ++i)
                #pragma unroll
                for (int j = 0; j < 4; ++j) {
                    aq[i][j] += ai[i] * wq[j];
                    ak[i][j] += ad[i] * wk[j];
                    av[i][j] += ad[i] * wv[j];
                }
        }
        __syncthreads();
    }

    float bqv[4], bkv[4], bvv[4];
    #pragma unroll
    for (int j = 0; j < 4; ++j) {
        bqv[j] = bq[c0 + tx * 4 + j];
        bkv[j] = bk[c0 + tx * 4 + j];
        bvv[j] = bv[c0 + tx * 4 + j];
    }
    // q,k token-major (q prescaled by 1/16)
    #pragma unroll
    for (int i = 0; i < 4; ++i) {
        const size_t row = (size_t)s * HW * CDIM + (size_t)(t0 + ty * 4 + i) * CDIM + c0 + tx * 4;
        bf16 tq[4], tk[4];
        #pragma unroll
        for (int j = 0; j < 4; ++j) {
            tq[j] = __float2bfloat16((aq[i][j] + bqv[j]) * 0.0625f);
            tk[j] = __float2bfloat16(ak[i][j] + bkv[j]);
        }
        *reinterpret_cast<uint2*>(&qo[row]) = *reinterpret_cast<uint2*>(tq);
        *reinterpret_cast<uint2*>(&ko[row]) = *reinterpret_cast<uint2*>(tk);
    }
    // v channel-major
    #pragma unroll
    for (int j = 0; j < 4; ++j) {
        const size_t base = (size_t)s * CDIM * HW + (size_t)(c0 + tx * 4 + j) * HW + t0 + ty * 4;
        bf16 tv[4];
        #pragma unroll
        for (int i = 0; i < 4; ++i) tv[i] = __float2bfloat16(av[i][j] + bvv[j]);
        *reinterpret_cast<uint2*>(&vt[base]) = *reinterpret_cast<uint2*>(tv);
    }
}

// ---------------------------------------------------------------------------
// Kernel 2: MFMA flash attention + residual + channel-major f32 output.
// Block = 4 waves x 16 q-rows = 64 q-rows. KV iterated in 32-token tiles.
// Wave-local softmax (rows owned by wave; S/O fragment rows coincide).
// ---------------------------------------------------------------------------
__global__ __launch_bounds__(256)
void flash_mfma_kernel(const bf16* __restrict__ q, const bf16* __restrict__ k,
                       const bf16* __restrict__ vt, const float* __restrict__ img,
                       float* __restrict__ out)
{
    // XCD-friendly decode: slice%8 == blockIdx.x%8
    const int bid = blockIdx.x;
    const int qt  = bid >> 5;
    const int rr_ = bid & 31;
    const int s   = (rr_ & 7) * 4 + (rr_ >> 3);
    const int t0  = qt * 64;

    const int tid  = threadIdx.x;
    const int wave = tid >> 6;
    const int lane = tid & 63;
    const int lo16 = lane & 15;
    const int hi4  = lane >> 4;     // 0..3

    __shared__ short Ks[KVT][264];      // K tile token-major [tok][c]
    __shared__ short Vs[CDIM][40];      // V tile channel-major [c][tok]
    __shared__ short Ps[4][16][40];     // per-wave P (bf16)

    // ---- Q A-fragments in registers (row = lo16 within wave's 16 rows) ----
    short8v qf[8];
    {
        const int qrow = t0 + wave * 16 + lo16;
        const bf16* qp = q + ((size_t)s * HW + qrow) * CDIM + hi4 * 8;
        #pragma unroll
        for (int kf = 0; kf < 8; ++kf)
            qf[kf] = *reinterpret_cast<const short8v*>(qp + kf * 32);
    }

    f32x4 Oacc[16];
    #pragma unroll
    for (int cf = 0; cf < 16; ++cf) Oacc[cf] = (f32x4){0.f, 0.f, 0.f, 0.f};
    float mrow[4] = {-1e30f, -1e30f, -1e30f, -1e30f};
    float lrow[4] = {0.f, 0.f, 0.f, 0.f};

    const bf16* kS  = k  + (size_t)s * HW * CDIM;
    const bf16* vtS = vt + (size_t)s * CDIM * HW;

    for (int kt = 0; kt < HW / KVT; ++kt) {
        __syncthreads();   // previous-iter LDS reads done
        // ---- stage K tile (32 tok x 256 c): thread t -> row t>>3, 4 chunks
        {
            const int row = tid >> 3;
            const bf16* src = kS + (size_t)(kt * KVT + row) * CDIM;
            #pragma unroll
            for (int u = 0; u < 4; ++u) {
                const int ch = (tid & 7) + u * 8;   // 0..31 (16B chunks)
                *reinterpret_cast<short8v*>(&Ks[row][ch * 8]) =
                    *reinterpret_cast<const short8v*>(src + ch * 8);
            }
            // stage V tile (256 c x 32 tok): thread t -> channel t, 4 chunks
            const bf16* vsrc = vtS + (size_t)tid * HW + kt * KVT;
            #pragma unroll
            for (int u = 0; u < 4; ++u)
                *reinterpret_cast<short8v*>(&Vs[tid][u * 8]) =
                    *reinterpret_cast<const short8v*>(vsrc + u * 8);
        }
        __syncthreads();

        // ---- QK^T: S[16 x 32] per wave; sa[cf] cf=0,1 ----
        f32x4 sa[2];
        sa[0] = (f32x4){0.f, 0.f, 0.f, 0.f};
        sa[1] = (f32x4){0.f, 0.f, 0.f, 0.f};
        #pragma unroll
        for (int ks = 0; ks < 8; ++ks) {
            #pragma unroll
            for (int cf = 0; cf < 2; ++cf) {
                short8v bfr = *reinterpret_cast<const short8v*>(
                    &Ks[cf * 16 + lo16][ks * 32 + hi4 * 8]);
                sa[cf] = __builtin_amdgcn_mfma_f32_16x16x32_bf16(qf[ks], bfr, sa[cf], 0, 0, 0);
            }
        }

        // ---- online softmax (wave-local). lane: rows 4*hi4+g, col cf*16+lo16
        float pm[4];
        #pragma unroll
        for (int g = 0; g < 4; ++g) pm[g] = fmaxf(sa[0][g], sa[1][g]);
        #pragma unroll
        for (int off = 1; off < 16; off <<= 1) {
            #pragma unroll
            for (int g = 0; g < 4; ++g) pm[g] = fmaxf(pm[g], __shfl_xor(pm[g], off));
        }
        float resc[4];
        #pragma unroll
        for (int g = 0; g < 4; ++g) {
            const float mn = fmaxf(mrow[g], pm[g]);
            resc[g] = __expf(mrow[g] - mn);
            mrow[g] = mn;
        }
        float ps[4] = {0.f, 0.f, 0.f, 0.f};
        short pb[2][4];
        #pragma unroll
        for (int cf = 0; cf < 2; ++cf) {
            #pragma unroll
            for (int g = 0; g < 4; ++g) {
                const float e = __expf(sa[cf][g] - mrow[g]);
                ps[g] += e;
                bf16 hb = __float2bfloat16(e);
                pb[cf][g] = *reinterpret_cast<short*>(&hb);
            }
        }
        #pragma unroll
        for (int off = 1; off < 16; off <<= 1) {
            #pragma unroll
            for (int g = 0; g < 4; ++g) ps[g] += __shfl_xor(ps[g], off);
        }
        #pragma unroll
        for (int g = 0; g < 4; ++g) lrow[g] = lrow[g] * resc[g] + ps[g];

        // rescale O (O rows == S rows per lane)
        #pragma unroll
        for (int cf = 0; cf < 16; ++cf) {
            #pragma unroll
            for (int g = 0; g < 4; ++g) Oacc[cf][g] *= resc[g];
        }

        // ---- P -> LDS (transpose to A-frag layout), wave-local ----
        #pragma unroll
        for (int cf = 0; cf < 2; ++cf)
            #pragma unroll
            for (int g = 0; g < 4; ++g)
                Ps[wave][4 * hi4 + g][cf * 16 + lo16] = pb[cf][g];
        // (compiler inserts lgkmcnt wait before dependent read below)

        // ---- PV: O[16 x 256] += P[16 x 32] @ V[32 x 256] ----
        short8v pa = *reinterpret_cast<const short8v*>(&Ps[wave][lo16][hi4 * 8]);
        #pragma unroll
        for (int cf = 0; cf < 16; ++cf) {
            short8v vb = *reinterpret_cast<const short8v*>(
                &Vs[cf * 16 + lo16][hi4 * 8]);
            Oacc[cf] = __builtin_amdgcn_mfma_f32_16x16x32_bf16(pa, vb, Oacc[cf], 0, 0, 0);
        }
    }

    // ---- epilogue: /l, +residual, store f32 channel-major ----
    float inv[4];
    #pragma unroll
    for (int g = 0; g < 4; ++g) inv[g] = 1.0f / lrow[g];
    const float* imgS = img + (size_t)s * CDIM * HW;
    float*       outS = out + (size_t)s * CDIM * HW;
    const int tt = t0 + wave * 16 + 4 * hi4;
    #pragma unroll
    for (int cf = 0; cf < 16; ++cf) {
        const int c = cf * 16 + lo16;
        const float4 r4 = *reinterpret_cast<const float4*>(imgS + (size_t)c * HW + tt);
        float4 o;
        o.x = Oacc[cf][0] * inv[0] + r4.x;
        o.y = Oacc[cf][1] * inv[1] + r4.y;
        o.z = Oacc[cf][2] * inv[2] + r4.z;
        o.w = Oacc[cf][3] * inv[3] + r4.w;
        *reinterpret_cast<float4*>(outS + (size_t)c * HW + tt) = o;
    }
}

// ---------------------------------------------------------------------------
extern "C" void kernel_launch(void* const* d_in, const int* in_sizes, int n_in,
                              void* d_out, int out_size, void* d_ws, size_t ws_size,
                              hipStream_t stream)
{
    const float* img = (const float*)d_in[0];
    const float* dep = (const float*)d_in[1];
    const float* Wq  = (const float*)d_in[2];
    const float* bq  = (const float*)d_in[3];
    const float* Wk  = (const float*)d_in[4];
    const float* bk  = (const float*)d_in[5];
    const float* Wv  = (const float*)d_in[6];
    const float* bv  = (const float*)d_in[7];
    float* out = (float*)d_out;

    const size_t npt  = (size_t)NSLICE * HW * CDIM;
    const size_t need = 3 * npt * sizeof(bf16);   // 48 MiB
    if (ws_size < need) {
        hipMemsetAsync(d_out, 0, (size_t)out_size * sizeof(float), stream);
        return;
    }

    bf16* q  = (bf16*)d_ws;        // token-major, prescaled
    bf16* k  = q + npt;            // token-major
    bf16* vt = k + npt;            // channel-major

    qkv_proj_kernel<<<dim3(16, 4, NSLICE), 256, 0, stream>>>(
        img, dep, Wq, bq, Wk, bk, Wv, bv, q, k, vt);

    flash_mfma_kernel<<<dim3(NSLICE * 16), 256, 0, stream>>>(q, k, vt, img, out);
}

// Round 5
// 165.279 us; speedup vs baseline: 11.0634x; 1.6833x over previous
//
#include <hip/hip_runtime.h>
#include <hip/hip_bf16.h>

typedef __hip_bfloat16 bf16;
typedef __attribute__((ext_vector_type(8))) short short8v;
typedef __attribute__((ext_vector_type(4))) float f32x4;

#define NSLICE 32   // B*S
#define HW     1024 // H*W
#define CDIM   256  // C1 == C2 == C
#define KVT    32   // kv tokens per flash inner tile

// ---------------------------------------------------------------------------
// Kernel 0: W^T prep. W f32 [cin][cout] -> wt bf16 [mat][cout][cin].
// Wq (mat 0) prescaled by 1/16 (softmax scale folded into q).
// ---------------------------------------------------------------------------
__global__ __launch_bounds__(256)
void wt_prep_kernel(const float* __restrict__ Wq, const float* __restrict__ Wk,
                    const float* __restrict__ Wv, bf16* __restrict__ wt)
{
    const int m = blockIdx.x >> 8;     // 0..2
    const int r = blockIdx.x & 255;    // cin row
    const int tid = threadIdx.x;       // cout
    const float* W = (m == 0) ? Wq : (m == 1) ? Wk : Wv;
    const float sc = (m == 0) ? 0.0625f : 1.0f;
    wt[((size_t)m << 16) + (size_t)tid * 256 + r] = __float2bfloat16(W[r * 256 + tid] * sc);
}

// ---------------------------------------------------------------------------
// Kernel 1: MFMA QKV projection.
//   img/dep : [slice][cin][t] f32 (channel-major)
//   wt      : bf16 [mat][cout][cin] (Wq prescaled)
//   q,k     : [slice][t][cout] bf16 token-major (q prescaled)
//   vt      : [slice][cout][t] bf16 channel-major
// Block: 64 tokens x 128 couts (chalf selects cout half). Wave: 64 t x 32 c.
// q/k: D[m=cout][n=tok] = mfma(Wt, X); v: D[m=tok][n=cout] = mfma(X, Wt).
// ---------------------------------------------------------------------------
__global__ __launch_bounds__(256)
void qkv_mfma_kernel(const float* __restrict__ img, const float* __restrict__ dep,
                     const bf16* __restrict__ wt,
                     const float* __restrict__ bq, const float* __restrict__ bk,
                     const float* __restrict__ bv,
                     bf16* __restrict__ qo, bf16* __restrict__ ko, bf16* __restrict__ vt)
{
    const int bid   = blockIdx.x;
    const int chalf = bid & 1;
    const int tt    = (bid >> 1) & 15;
    const int s     = bid >> 5;
    const int t0    = tt * 64;

    const int tid  = threadIdx.x;
    const int wave = tid >> 6;
    const int lane = tid & 63;
    const int lo16 = lane & 15;
    const int hi4  = lane >> 4;
    const int cw0  = chalf * 128 + wave * 32;   // wave's cout base

    __shared__ short Ai[64][40];   // img tile [t][cin_local], stride 40 (80B)
    __shared__ short Ad[64][40];   // dep tile

    // staging mapping: so = cin octet (0..3), st = token (0..63)
    const int so = tid >> 6;
    const int st = tid & 63;

    const float* imgS = img + (size_t)s * CDIM * HW + t0;
    const float* depS = dep + (size_t)s * CDIM * HW + t0;

    const bf16* wtq = wt;
    const bf16* wtk = wt + (1 << 16);
    const bf16* wtv = wt + (2 << 16);

    f32x4 aq[2][4], ak[2][4], av[4][2];
    #pragma unroll
    for (int a = 0; a < 2; ++a)
        #pragma unroll
        for (int b = 0; b < 4; ++b) {
            aq[a][b] = (f32x4){0.f, 0.f, 0.f, 0.f};
            ak[a][b] = (f32x4){0.f, 0.f, 0.f, 0.f};
            av[b][a] = (f32x4){0.f, 0.f, 0.f, 0.f};
        }

    // prefetch chunk 0 (8 coalesced f32 rows per mat per thread)
    float ri[8], rd[8];
    #pragma unroll
    for (int j = 0; j < 8; ++j) {
        ri[j] = imgS[(size_t)(so * 8 + j) * HW + st];
        rd[j] = depS[(size_t)(so * 8 + j) * HW + st];
    }

    for (int kc = 0; kc < 8; ++kc) {
        __syncthreads();   // previous-iter frag reads done
        {
            short ti[8], td[8];
            #pragma unroll
            for (int j = 0; j < 8; ++j) {
                bf16 hi = __float2bfloat16(ri[j]);
                bf16 hd = __float2bfloat16(rd[j]);
                ti[j] = *reinterpret_cast<short*>(&hi);
                td[j] = *reinterpret_cast<short*>(&hd);
            }
            *reinterpret_cast<short8v*>(&Ai[st][so * 8]) = *reinterpret_cast<short8v*>(ti);
            *reinterpret_cast<short8v*>(&Ad[st][so * 8]) = *reinterpret_cast<short8v*>(td);
        }
        __syncthreads();

        if (kc < 7) {   // prefetch next chunk, overlaps MFMA below
            #pragma unroll
            for (int j = 0; j < 8; ++j) {
                ri[j] = imgS[(size_t)((kc + 1) * 32 + so * 8 + j) * HW + st];
                rd[j] = depS[(size_t)((kc + 1) * 32 + so * 8 + j) * HW + st];
            }
        }

        // X fragments (shared between B-role for q/k and A-role for v)
        short8v xi[4], xd[4];
        #pragma unroll
        for (int nf = 0; nf < 4; ++nf) {
            xi[nf] = *reinterpret_cast<const short8v*>(&Ai[nf * 16 + lo16][hi4 * 8]);
            xd[nf] = *reinterpret_cast<const short8v*>(&Ad[nf * 16 + lo16][hi4 * 8]);
        }
        // W^T fragments (global, L2-hot)
        const int koff = kc * 32 + hi4 * 8;
        short8v wqf[2], wkf[2], wvf[2];
        #pragma unroll
        for (int mf = 0; mf < 2; ++mf) {
            const size_t wrow = (size_t)(cw0 + mf * 16 + lo16) * 256 + koff;
            wqf[mf] = *reinterpret_cast<const short8v*>(wtq + wrow);
            wkf[mf] = *reinterpret_cast<const short8v*>(wtk + wrow);
            wvf[mf] = *reinterpret_cast<const short8v*>(wtv + wrow);
        }

        #pragma unroll
        for (int mf = 0; mf < 2; ++mf)
            #pragma unroll
            for (int nf = 0; nf < 4; ++nf) {
                aq[mf][nf] = __builtin_amdgcn_mfma_f32_16x16x32_bf16(wqf[mf], xi[nf], aq[mf][nf], 0, 0, 0);
                ak[mf][nf] = __builtin_amdgcn_mfma_f32_16x16x32_bf16(wkf[mf], xd[nf], ak[mf][nf], 0, 0, 0);
            }
        #pragma unroll
        for (int mf = 0; mf < 4; ++mf)
            #pragma unroll
            for (int nf = 0; nf < 2; ++nf)
                av[mf][nf] = __builtin_amdgcn_mfma_f32_16x16x32_bf16(xd[mf], wvf[nf], av[mf][nf], 0, 0, 0);
    }

    // ---- epilogue ----
    // q/k: lane: token = t0 + nf*16 + lo16 ; cout = cw0 + mf*16 + 4*hi4 + g
    #pragma unroll
    for (int mf = 0; mf < 2; ++mf) {
        const int cb = cw0 + mf * 16 + 4 * hi4;
        const float4 b4q = *reinterpret_cast<const float4*>(bq + cb);
        const float4 b4k = *reinterpret_cast<const float4*>(bk + cb);
        const float bqa[4] = {b4q.x * 0.0625f, b4q.y * 0.0625f, b4q.z * 0.0625f, b4q.w * 0.0625f};
        const float bka[4] = {b4k.x, b4k.y, b4k.z, b4k.w};
        #pragma unroll
        for (int nf = 0; nf < 4; ++nf) {
            const int tok = t0 + nf * 16 + lo16;
            bf16 tq[4], tk[4];
            #pragma unroll
            for (int g = 0; g < 4; ++g) {
                tq[g] = __float2bfloat16(aq[mf][nf][g] + bqa[g]);
                tk[g] = __float2bfloat16(ak[mf][nf][g] + bka[g]);
            }
            const size_t base = ((size_t)s * HW + tok) * CDIM + cb;
            *reinterpret_cast<uint2*>(&qo[base]) = *reinterpret_cast<uint2*>(tq);
            *reinterpret_cast<uint2*>(&ko[base]) = *reinterpret_cast<uint2*>(tk);
        }
    }
    // v: lane: cout = cw0 + nf*16 + lo16 ; token = t0 + mf*16 + 4*hi4 + g
    #pragma unroll
    for (int nf = 0; nf < 2; ++nf) {
        const int c = cw0 + nf * 16 + lo16;
        const float bvv = bv[c];
        #pragma unroll
        for (int mf = 0; mf < 4; ++mf) {
            const int tb = t0 + mf * 16 + 4 * hi4;
            bf16 tv[4];
            #pragma unroll
            for (int g = 0; g < 4; ++g)
                tv[g] = __float2bfloat16(av[mf][nf][g] + bvv);
            *reinterpret_cast<uint2*>(&vt[((size_t)s * CDIM + c) * HW + tb]) =
                *reinterpret_cast<uint2*>(tv);
        }
    }
}

// ---------------------------------------------------------------------------
// Kernel 2: MFMA flash attention + residual + channel-major f32 output.
// (unchanged from round 4)
// ---------------------------------------------------------------------------
__global__ __launch_bounds__(256)
void flash_mfma_kernel(const bf16* __restrict__ q, const bf16* __restrict__ k,
                       const bf16* __restrict__ vt, const float* __restrict__ img,
                       float* __restrict__ out)
{
    const int bid = blockIdx.x;
    const int qt  = bid >> 5;
    const int rr_ = bid & 31;
    const int s   = (rr_ & 7) * 4 + (rr_ >> 3);
    const int t0  = qt * 64;

    const int tid  = threadIdx.x;
    const int wave = tid >> 6;
    const int lane = tid & 63;
    const int lo16 = lane & 15;
    const int hi4  = lane >> 4;

    __shared__ short Ks[KVT][264];
    __shared__ short Vs[CDIM][40];
    __shared__ short Ps[4][16][40];

    short8v qf[8];
    {
        const int qrow = t0 + wave * 16 + lo16;
        const bf16* qp = q + ((size_t)s * HW + qrow) * CDIM + hi4 * 8;
        #pragma unroll
        for (int kf = 0; kf < 8; ++kf)
            qf[kf] = *reinterpret_cast<const short8v*>(qp + kf * 32);
    }

    f32x4 Oacc[16];
    #pragma unroll
    for (int cf = 0; cf < 16; ++cf) Oacc[cf] = (f32x4){0.f, 0.f, 0.f, 0.f};
    float mrow[4] = {-1e30f, -1e30f, -1e30f, -1e30f};
    float lrow[4] = {0.f, 0.f, 0.f, 0.f};

    const bf16* kS  = k  + (size_t)s * HW * CDIM;
    const bf16* vtS = vt + (size_t)s * CDIM * HW;

    for (int kt = 0; kt < HW / KVT; ++kt) {
        __syncthreads();
        {
            const int row = tid >> 3;
            const bf16* src = kS + (size_t)(kt * KVT + row) * CDIM;
            #pragma unroll
            for (int u = 0; u < 4; ++u) {
                const int ch = (tid & 7) + u * 8;
                *reinterpret_cast<short8v*>(&Ks[row][ch * 8]) =
                    *reinterpret_cast<const short8v*>(src + ch * 8);
            }
            const bf16* vsrc = vtS + (size_t)tid * HW + kt * KVT;
            #pragma unroll
            for (int u = 0; u < 4; ++u)
                *reinterpret_cast<short8v*>(&Vs[tid][u * 8]) =
                    *reinterpret_cast<const short8v*>(vsrc + u * 8);
        }
        __syncthreads();

        f32x4 sa[2];
        sa[0] = (f32x4){0.f, 0.f, 0.f, 0.f};
        sa[1] = (f32x4){0.f, 0.f, 0.f, 0.f};
        #pragma unroll
        for (int ks = 0; ks < 8; ++ks) {
            #pragma unroll
            for (int cf = 0; cf < 2; ++cf) {
                short8v bfr = *reinterpret_cast<const short8v*>(
                    &Ks[cf * 16 + lo16][ks * 32 + hi4 * 8]);
                sa[cf] = __builtin_amdgcn_mfma_f32_16x16x32_bf16(qf[ks], bfr, sa[cf], 0, 0, 0);
            }
        }

        float pm[4];
        #pragma unroll
        for (int g = 0; g < 4; ++g) pm[g] = fmaxf(sa[0][g], sa[1][g]);
        #pragma unroll
        for (int off = 1; off < 16; off <<= 1) {
            #pragma unroll
            for (int g = 0; g < 4; ++g) pm[g] = fmaxf(pm[g], __shfl_xor(pm[g], off));
        }
        float resc[4];
        #pragma unroll
        for (int g = 0; g < 4; ++g) {
            const float mn = fmaxf(mrow[g], pm[g]);
            resc[g] = __expf(mrow[g] - mn);
            mrow[g] = mn;
        }
        float ps[4] = {0.f, 0.f, 0.f, 0.f};
        short pb[2][4];
        #pragma unroll
        for (int cf = 0; cf < 2; ++cf) {
            #pragma unroll
            for (int g = 0; g < 4; ++g) {
                const float e = __expf(sa[cf][g] - mrow[g]);
                ps[g] += e;
                bf16 hb = __float2bfloat16(e);
                pb[cf][g] = *reinterpret_cast<short*>(&hb);
            }
        }
        #pragma unroll
        for (int off = 1; off < 16; off <<= 1) {
            #pragma unroll
            for (int g = 0; g < 4; ++g) ps[g] += __shfl_xor(ps[g], off);
        }
        #pragma unroll
        for (int g = 0; g < 4; ++g) lrow[g] = lrow[g] * resc[g] + ps[g];

        #pragma unroll
        for (int cf = 0; cf < 16; ++cf) {
            #pragma unroll
            for (int g = 0; g < 4; ++g) Oacc[cf][g] *= resc[g];
        }

        #pragma unroll
        for (int cf = 0; cf < 2; ++cf)
            #pragma unroll
            for (int g = 0; g < 4; ++g)
                Ps[wave][4 * hi4 + g][cf * 16 + lo16] = pb[cf][g];

        short8v pa = *reinterpret_cast<const short8v*>(&Ps[wave][lo16][hi4 * 8]);
        #pragma unroll
        for (int cf = 0; cf < 16; ++cf) {
            short8v vb = *reinterpret_cast<const short8v*>(
                &Vs[cf * 16 + lo16][hi4 * 8]);
            Oacc[cf] = __builtin_amdgcn_mfma_f32_16x16x32_bf16(pa, vb, Oacc[cf], 0, 0, 0);
        }
    }

    float inv[4];
    #pragma unroll
    for (int g = 0; g < 4; ++g) inv[g] = 1.0f / lrow[g];
    const float* imgS = img + (size_t)s * CDIM * HW;
    float*       outS = out + (size_t)s * CDIM * HW;
    const int tt = t0 + wave * 16 + 4 * hi4;
    #pragma unroll
    for (int cf = 0; cf < 16; ++cf) {
        const int c = cf * 16 + lo16;
        const float4 r4 = *reinterpret_cast<const float4*>(imgS + (size_t)c * HW + tt);
        float4 o;
        o.x = Oacc[cf][0] * inv[0] + r4.x;
        o.y = Oacc[cf][1] * inv[1] + r4.y;
        o.z = Oacc[cf][2] * inv[2] + r4.z;
        o.w = Oacc[cf][3] * inv[3] + r4.w;
        *reinterpret_cast<float4*>(outS + (size_t)c * HW + tt) = o;
    }
}

// ---------------------------------------------------------------------------
extern "C" void kernel_launch(void* const* d_in, const int* in_sizes, int n_in,
                              void* d_out, int out_size, void* d_ws, size_t ws_size,
                              hipStream_t stream)
{
    const float* img = (const float*)d_in[0];
    const float* dep = (const float*)d_in[1];
    const float* Wq  = (const float*)d_in[2];
    const float* bq  = (const float*)d_in[3];
    const float* Wk  = (const float*)d_in[4];
    const float* bk  = (const float*)d_in[5];
    const float* Wv  = (const float*)d_in[6];
    const float* bv  = (const float*)d_in[7];
    float* out = (float*)d_out;

    const size_t npt  = (size_t)NSLICE * HW * CDIM;
    const size_t need = 3 * npt * sizeof(bf16) + 3 * 65536 * sizeof(bf16);
    if (ws_size < need) {
        hipMemsetAsync(d_out, 0, (size_t)out_size * sizeof(float), stream);
        return;
    }

    bf16* q  = (bf16*)d_ws;        // token-major, prescaled
    bf16* k  = q + npt;            // token-major
    bf16* vt = k + npt;            // channel-major
    bf16* wt = vt + npt;           // [3][256][256] W^T

    wt_prep_kernel<<<dim3(3 * 256), 256, 0, stream>>>(Wq, Wk, Wv, wt);

    qkv_mfma_kernel<<<dim3(NSLICE * 32), 256, 0, stream>>>(
        img, dep, wt, bq, bk, bv, q, k, vt);

    flash_mfma_kernel<<<dim3(NSLICE * 16), 256, 0, stream>>>(q, k, vt, img, out);
}

// Round 6
// 159.739 us; speedup vs baseline: 11.4472x; 1.0347x over previous
//
#include <hip/hip_runtime.h>
#include <hip/hip_bf16.h>

typedef __hip_bfloat16 bf16;
typedef __attribute__((ext_vector_type(8))) short short8v;
typedef __attribute__((ext_vector_type(4))) float f32x4;

#define NSLICE 32   // B*S
#define HW     1024 // H*W
#define CDIM   256  // C1 == C2 == C
#define KVT    32   // kv tokens per flash inner tile

// ---------------------------------------------------------------------------
// Kernel 0: W^T prep. W f32 [cin][cout] -> wt bf16 [mat][cout][cin].
// Wq (mat 0) prescaled by 1/16 (softmax scale folded into q).
// ---------------------------------------------------------------------------
__global__ __launch_bounds__(256)
void wt_prep_kernel(const float* __restrict__ Wq, const float* __restrict__ Wk,
                    const float* __restrict__ Wv, bf16* __restrict__ wt)
{
    const int m = blockIdx.x >> 8;     // 0..2
    const int r = blockIdx.x & 255;    // cin row
    const int tid = threadIdx.x;       // cout
    const float* W = (m == 0) ? Wq : (m == 1) ? Wk : Wv;
    const float sc = (m == 0) ? 0.0625f : 1.0f;
    wt[((size_t)m << 16) + (size_t)tid * 256 + r] = __float2bfloat16(W[r * 256 + tid] * sc);
}

// ---------------------------------------------------------------------------
// Kernel 1: MFMA QKV projection (unchanged from round 5).
// ---------------------------------------------------------------------------
__global__ __launch_bounds__(256)
void qkv_mfma_kernel(const float* __restrict__ img, const float* __restrict__ dep,
                     const bf16* __restrict__ wt,
                     const float* __restrict__ bq, const float* __restrict__ bk,
                     const float* __restrict__ bv,
                     bf16* __restrict__ qo, bf16* __restrict__ ko, bf16* __restrict__ vt)
{
    const int bid   = blockIdx.x;
    const int chalf = bid & 1;
    const int tt    = (bid >> 1) & 15;
    const int s     = bid >> 5;
    const int t0    = tt * 64;

    const int tid  = threadIdx.x;
    const int wave = tid >> 6;
    const int lane = tid & 63;
    const int lo16 = lane & 15;
    const int hi4  = lane >> 4;
    const int cw0  = chalf * 128 + wave * 32;

    __shared__ short Ai[64][40];
    __shared__ short Ad[64][40];

    const int so = tid >> 6;
    const int st = tid & 63;

    const float* imgS = img + (size_t)s * CDIM * HW + t0;
    const float* depS = dep + (size_t)s * CDIM * HW + t0;

    const bf16* wtq = wt;
    const bf16* wtk = wt + (1 << 16);
    const bf16* wtv = wt + (2 << 16);

    f32x4 aq[2][4], ak[2][4], av[4][2];
    #pragma unroll
    for (int a = 0; a < 2; ++a)
        #pragma unroll
        for (int b = 0; b < 4; ++b) {
            aq[a][b] = (f32x4){0.f, 0.f, 0.f, 0.f};
            ak[a][b] = (f32x4){0.f, 0.f, 0.f, 0.f};
            av[b][a] = (f32x4){0.f, 0.f, 0.f, 0.f};
        }

    float ri[8], rd[8];
    #pragma unroll
    for (int j = 0; j < 8; ++j) {
        ri[j] = imgS[(size_t)(so * 8 + j) * HW + st];
        rd[j] = depS[(size_t)(so * 8 + j) * HW + st];
    }

    for (int kc = 0; kc < 8; ++kc) {
        __syncthreads();
        {
            short ti[8], td[8];
            #pragma unroll
            for (int j = 0; j < 8; ++j) {
                bf16 hi = __float2bfloat16(ri[j]);
                bf16 hd = __float2bfloat16(rd[j]);
                ti[j] = *reinterpret_cast<short*>(&hi);
                td[j] = *reinterpret_cast<short*>(&hd);
            }
            *reinterpret_cast<short8v*>(&Ai[st][so * 8]) = *reinterpret_cast<short8v*>(ti);
            *reinterpret_cast<short8v*>(&Ad[st][so * 8]) = *reinterpret_cast<short8v*>(td);
        }
        __syncthreads();

        if (kc < 7) {
            #pragma unroll
            for (int j = 0; j < 8; ++j) {
                ri[j] = imgS[(size_t)((kc + 1) * 32 + so * 8 + j) * HW + st];
                rd[j] = depS[(size_t)((kc + 1) * 32 + so * 8 + j) * HW + st];
            }
        }

        short8v xi[4], xd[4];
        #pragma unroll
        for (int nf = 0; nf < 4; ++nf) {
            xi[nf] = *reinterpret_cast<const short8v*>(&Ai[nf * 16 + lo16][hi4 * 8]);
            xd[nf] = *reinterpret_cast<const short8v*>(&Ad[nf * 16 + lo16][hi4 * 8]);
        }
        const int koff = kc * 32 + hi4 * 8;
        short8v wqf[2], wkf[2], wvf[2];
        #pragma unroll
        for (int mf = 0; mf < 2; ++mf) {
            const size_t wrow = (size_t)(cw0 + mf * 16 + lo16) * 256 + koff;
            wqf[mf] = *reinterpret_cast<const short8v*>(wtq + wrow);
            wkf[mf] = *reinterpret_cast<const short8v*>(wtk + wrow);
            wvf[mf] = *reinterpret_cast<const short8v*>(wtv + wrow);
        }

        #pragma unroll
        for (int mf = 0; mf < 2; ++mf)
            #pragma unroll
            for (int nf = 0; nf < 4; ++nf) {
                aq[mf][nf] = __builtin_amdgcn_mfma_f32_16x16x32_bf16(wqf[mf], xi[nf], aq[mf][nf], 0, 0, 0);
                ak[mf][nf] = __builtin_amdgcn_mfma_f32_16x16x32_bf16(wkf[mf], xd[nf], ak[mf][nf], 0, 0, 0);
            }
        #pragma unroll
        for (int mf = 0; mf < 4; ++mf)
            #pragma unroll
            for (int nf = 0; nf < 2; ++nf)
                av[mf][nf] = __builtin_amdgcn_mfma_f32_16x16x32_bf16(xd[mf], wvf[nf], av[mf][nf], 0, 0, 0);
    }

    #pragma unroll
    for (int mf = 0; mf < 2; ++mf) {
        const int cb = cw0 + mf * 16 + 4 * hi4;
        const float4 b4q = *reinterpret_cast<const float4*>(bq + cb);
        const float4 b4k = *reinterpret_cast<const float4*>(bk + cb);
        const float bqa[4] = {b4q.x * 0.0625f, b4q.y * 0.0625f, b4q.z * 0.0625f, b4q.w * 0.0625f};
        const float bka[4] = {b4k.x, b4k.y, b4k.z, b4k.w};
        #pragma unroll
        for (int nf = 0; nf < 4; ++nf) {
            const int tok = t0 + nf * 16 + lo16;
            bf16 tq[4], tk[4];
            #pragma unroll
            for (int g = 0; g < 4; ++g) {
                tq[g] = __float2bfloat16(aq[mf][nf][g] + bqa[g]);
                tk[g] = __float2bfloat16(ak[mf][nf][g] + bka[g]);
            }
            const size_t base = ((size_t)s * HW + tok) * CDIM + cb;
            *reinterpret_cast<uint2*>(&qo[base]) = *reinterpret_cast<uint2*>(tq);
            *reinterpret_cast<uint2*>(&ko[base]) = *reinterpret_cast<uint2*>(tk);
        }
    }
    #pragma unroll
    for (int nf = 0; nf < 2; ++nf) {
        const int c = cw0 + nf * 16 + lo16;
        const float bvv = bv[c];
        #pragma unroll
        for (int mf = 0; mf < 4; ++mf) {
            const int tb = t0 + mf * 16 + 4 * hi4;
            bf16 tv[4];
            #pragma unroll
            for (int g = 0; g < 4; ++g)
                tv[g] = __float2bfloat16(av[mf][nf][g] + bvv);
            *reinterpret_cast<uint2*>(&vt[((size_t)s * CDIM + c) * HW + tb]) =
                *reinterpret_cast<uint2*>(tv);
        }
    }
}

// ---------------------------------------------------------------------------
// Kernel 2: MFMA flash attention, async-staged (T14) + coalesced V loads.
// Block = 4 waves x 16 q-rows. KV tiles of 32 tokens, register-prefetched.
// ---------------------------------------------------------------------------
__global__ __launch_bounds__(256)
void flash_mfma_kernel(const bf16* __restrict__ q, const bf16* __restrict__ k,
                       const bf16* __restrict__ vt, const float* __restrict__ img,
                       float* __restrict__ out)
{
    const int bid = blockIdx.x;
    const int qt  = bid >> 5;
    const int rr_ = bid & 31;
    const int s   = (rr_ & 7) * 4 + (rr_ >> 3);
    const int t0  = qt * 64;

    const int tid  = threadIdx.x;
    const int wave = tid >> 6;
    const int lane = tid & 63;
    const int lo16 = lane & 15;
    const int hi4  = lane >> 4;

    __shared__ short Ks[KVT][264];
    __shared__ short Vs[CDIM][40];
    __shared__ short Ps[4][16][40];

    short8v qf[8];
    {
        const int qrow = t0 + wave * 16 + lo16;
        const bf16* qp = q + ((size_t)s * HW + qrow) * CDIM + hi4 * 8;
        #pragma unroll
        for (int kf = 0; kf < 8; ++kf)
            qf[kf] = *reinterpret_cast<const short8v*>(qp + kf * 32);
    }

    f32x4 Oacc[16];
    #pragma unroll
    for (int cf = 0; cf < 16; ++cf) Oacc[cf] = (f32x4){0.f, 0.f, 0.f, 0.f};
    float mrow[4] = {-1e30f, -1e30f, -1e30f, -1e30f};
    float lrow[4] = {0.f, 0.f, 0.f, 0.f};

    const bf16* kS  = k  + (size_t)s * HW * CDIM;
    const bf16* vtS = vt + (size_t)s * CDIM * HW;

    // staging mappings
    const int krow = tid >> 3;            // 0..31 (K tile row)
    const int kch  = tid & 7;             // 16B chunk index base
    const int vcl  = lane >> 2;           // channel-within-16 group
    const int vtq  = (lane & 3) * 8;      // token offset (8 tok = 16B)

    short8v kreg[4], vreg[4];
    {   // prologue: prefetch tile 0
        const bf16* src = kS;
        #pragma unroll
        for (int u = 0; u < 4; ++u)
            kreg[u] = *reinterpret_cast<const short8v*>(src + (size_t)krow * CDIM + (kch + u * 8) * 8);
        #pragma unroll
        for (int u = 0; u < 4; ++u) {
            const int c = wave * 64 + u * 16 + vcl;
            vreg[u] = *reinterpret_cast<const short8v*>(vtS + (size_t)c * HW + vtq);
        }
    }

    for (int kt = 0; kt < HW / KVT; ++kt) {
        __syncthreads();   // previous-iter LDS reads done
        // publish prefetched tile to LDS
        #pragma unroll
        for (int u = 0; u < 4; ++u)
            *reinterpret_cast<short8v*>(&Ks[krow][(kch + u * 8) * 8]) = kreg[u];
        #pragma unroll
        for (int u = 0; u < 4; ++u)
            *reinterpret_cast<short8v*>(&Vs[wave * 64 + u * 16 + vcl][vtq]) = vreg[u];
        __syncthreads();

        // prefetch next tile into registers; overlaps with compute below
        if (kt + 1 < HW / KVT) {
            const bf16* src = kS + (size_t)(kt + 1) * KVT * CDIM;
            #pragma unroll
            for (int u = 0; u < 4; ++u)
                kreg[u] = *reinterpret_cast<const short8v*>(src + (size_t)krow * CDIM + (kch + u * 8) * 8);
            #pragma unroll
            for (int u = 0; u < 4; ++u) {
                const int c = wave * 64 + u * 16 + vcl;
                vreg[u] = *reinterpret_cast<const short8v*>(vtS + (size_t)c * HW + (kt + 1) * KVT + vtq);
            }
        }

        // ---- QK^T: S[16 x 32] per wave ----
        f32x4 sa[2];
        sa[0] = (f32x4){0.f, 0.f, 0.f, 0.f};
        sa[1] = (f32x4){0.f, 0.f, 0.f, 0.f};
        __builtin_amdgcn_s_setprio(1);
        #pragma unroll
        for (int ks = 0; ks < 8; ++ks) {
            #pragma unroll
            for (int cf = 0; cf < 2; ++cf) {
                short8v bfr = *reinterpret_cast<const short8v*>(
                    &Ks[cf * 16 + lo16][ks * 32 + hi4 * 8]);
                sa[cf] = __builtin_amdgcn_mfma_f32_16x16x32_bf16(qf[ks], bfr, sa[cf], 0, 0, 0);
            }
        }
        __builtin_amdgcn_s_setprio(0);

        // ---- online softmax (wave-local) ----
        float pm[4];
        #pragma unroll
        for (int g = 0; g < 4; ++g) pm[g] = fmaxf(sa[0][g], sa[1][g]);
        #pragma unroll
        for (int off = 1; off < 16; off <<= 1) {
            #pragma unroll
            for (int g = 0; g < 4; ++g) pm[g] = fmaxf(pm[g], __shfl_xor(pm[g], off));
        }
        float resc[4];
        #pragma unroll
        for (int g = 0; g < 4; ++g) {
            const float mn = fmaxf(mrow[g], pm[g]);
            resc[g] = __expf(mrow[g] - mn);
            mrow[g] = mn;
        }
        float ps[4] = {0.f, 0.f, 0.f, 0.f};
        short pb[2][4];
        #pragma unroll
        for (int cf = 0; cf < 2; ++cf) {
            #pragma unroll
            for (int g = 0; g < 4; ++g) {
                const float e = __expf(sa[cf][g] - mrow[g]);
                ps[g] += e;
                bf16 hb = __float2bfloat16(e);
                pb[cf][g] = *reinterpret_cast<short*>(&hb);
            }
        }
        #pragma unroll
        for (int off = 1; off < 16; off <<= 1) {
            #pragma unroll
            for (int g = 0; g < 4; ++g) ps[g] += __shfl_xor(ps[g], off);
        }
        #pragma unroll
        for (int g = 0; g < 4; ++g) lrow[g] = lrow[g] * resc[g] + ps[g];

        #pragma unroll
        for (int cf = 0; cf < 16; ++cf) {
            #pragma unroll
            for (int g = 0; g < 4; ++g) Oacc[cf][g] *= resc[g];
        }

        // ---- P -> LDS (per-wave transpose to A-frag layout) ----
        #pragma unroll
        for (int cf = 0; cf < 2; ++cf)
            #pragma unroll
            for (int g = 0; g < 4; ++g)
                Ps[wave][4 * hi4 + g][cf * 16 + lo16] = pb[cf][g];

        // ---- PV: O[16 x 256] += P[16 x 32] @ V[32 x 256] ----
        short8v pa = *reinterpret_cast<const short8v*>(&Ps[wave][lo16][hi4 * 8]);
        __builtin_amdgcn_s_setprio(1);
        #pragma unroll
        for (int cf = 0; cf < 16; ++cf) {
            short8v vb = *reinterpret_cast<const short8v*>(
                &Vs[cf * 16 + lo16][hi4 * 8]);
            Oacc[cf] = __builtin_amdgcn_mfma_f32_16x16x32_bf16(pa, vb, Oacc[cf], 0, 0, 0);
        }
        __builtin_amdgcn_s_setprio(0);
    }

    // ---- epilogue: /l, +residual, store f32 channel-major ----
    float inv[4];
    #pragma unroll
    for (int g = 0; g < 4; ++g) inv[g] = 1.0f / lrow[g];
    const float* imgS = img + (size_t)s * CDIM * HW;
    float*       outS = out + (size_t)s * CDIM * HW;
    const int tt = t0 + wave * 16 + 4 * hi4;
    #pragma unroll
    for (int cf = 0; cf < 16; ++cf) {
        const int c = cf * 16 + lo16;
        const float4 r4 = *reinterpret_cast<const float4*>(imgS + (size_t)c * HW + tt);
        float4 o;
        o.x = Oacc[cf][0] * inv[0] + r4.x;
        o.y = Oacc[cf][1] * inv[1] + r4.y;
        o.z = Oacc[cf][2] * inv[2] + r4.z;
        o.w = Oacc[cf][3] * inv[3] + r4.w;
        *reinterpret_cast<float4*>(outS + (size_t)c * HW + tt) = o;
    }
}

// ---------------------------------------------------------------------------
extern "C" void kernel_launch(void* const* d_in, const int* in_sizes, int n_in,
                              void* d_out, int out_size, void* d_ws, size_t ws_size,
                              hipStream_t stream)
{
    const float* img = (const float*)d_in[0];
    const float* dep = (const float*)d_in[1];
    const float* Wq  = (const float*)d_in[2];
    const float* bq  = (const float*)d_in[3];
    const float* Wk  = (const float*)d_in[4];
    const float* bk  = (const float*)d_in[5];
    const float* Wv  = (const float*)d_in[6];
    const float* bv  = (const float*)d_in[7];
    float* out = (float*)d_out;

    const size_t npt  = (size_t)NSLICE * HW * CDIM;
    const size_t need = 3 * npt * sizeof(bf16) + 3 * 65536 * sizeof(bf16);
    if (ws_size < need) {
        hipMemsetAsync(d_out, 0, (size_t)out_size * sizeof(float), stream);
        return;
    }

    bf16* q  = (bf16*)d_ws;        // token-major, prescaled
    bf16* k  = q + npt;            // token-major
    bf16* vt = k + npt;            // channel-major
    bf16* wt = vt + npt;           // [3][256][256] W^T

    wt_prep_kernel<<<dim3(3 * 256), 256, 0, stream>>>(Wq, Wk, Wv, wt);

    qkv_mfma_kernel<<<dim3(NSLICE * 32), 256, 0, stream>>>(
        img, dep, wt, bq, bk, bv, q, k, vt);

    flash_mfma_kernel<<<dim3(NSLICE * 16), 256, 0, stream>>>(q, k, vt, img, out);
}